// Round 15
// baseline (173.283 us; speedup 1.0000x reference)
//
#include <hip/hip_runtime.h>

// RGCN layer with skip on MI355X.
// out[n] = bias + skip_bias + x[n]@skipW^T + h[n]@rootW + sum_{e: dst=n} ew[e]*(h[src]@rel[etype])
//
// Round 15: GEMM grid-bound fix. BM 64->32, 128-thread blocks (2 waves x
// 32x64 tile) -> 1563 blocks = 6.1 blocks/CU (was 3.05, occupancy 24%).
// BN stays 128 so A/S is still read ONCE from HBM; extra Bt re-reads are
// L2-resident (320 KB). zero kernel replaced by hipMemsetAsync.
// accum / CSR / prep unchanged from round 14.

constexpr int DIM  = 128;
constexpr int BM   = 64;
constexpr int KC   = 32;
constexpr int BPAD = 4;
constexpr int KTOT = 1280;        // 8*128 (S) + 128 (h) + 128 (x)
constexpr int SCAN_CHUNK = 2048;  // elements per scan block (256 thr x 8)

typedef __attribute__((ext_vector_type(8))) short     short8v;
typedef __attribute__((ext_vector_type(8))) unsigned short ushort8v;
typedef __attribute__((ext_vector_type(4))) float     float4v;
typedef __attribute__((ext_vector_type(4))) unsigned  uint4v;

__device__ __forceinline__ unsigned short f2bf(float x) {
    union { float f; unsigned u; } c; c.f = x;
    unsigned u = c.u;
    u += 0x7fffu + ((u >> 16) & 1u);   // round-to-nearest-even
    return (unsigned short)(u >> 16);
}
__device__ __forceinline__ float bits2f(unsigned u) {
    union { unsigned u; float f; } c; c.u = u; return c.f;
}

// async global->LDS, 16 B per lane; LDS dest = wave-uniform base + lane*16
__device__ __forceinline__ void gload_lds16(const void* g, void* l) {
    __builtin_amdgcn_global_load_lds(
        (const __attribute__((address_space(1))) unsigned int*)g,
        (__attribute__((address_space(3))) unsigned int*)l,
        16, 0, 0);
}

// ---------------------------------------------------------------------------
// merged prep: blocks [0,nb1) cvt h->hb; [nb1,2*nb1) cvt x->xb;
// [2*nb1, 2*nb1+nbB) repack Bt.
// Bt[f][k]: k<1024 -> relF[k][f]; 1024..1151 -> rootW[k-1024][f];
//           1152..1279 -> skipW[f][k-1152]
// ---------------------------------------------------------------------------
__global__ __launch_bounds__(256) void prep_kernel(
    const float* __restrict__ h, const float* __restrict__ x,
    const float* __restrict__ relF, const float* __restrict__ rootW,
    const float* __restrict__ skipW,
    unsigned short* __restrict__ hb, unsigned short* __restrict__ xb,
    unsigned short* __restrict__ Bt, int n8, int nb1)
{
    const int b = blockIdx.x;
    if (b < 2 * nb1) {
        const float* __restrict__ src = (b < nb1) ? h : x;
        unsigned short* __restrict__ dst = (b < nb1) ? hb : xb;
        int i = (b < nb1 ? b : b - nb1) * 256 + threadIdx.x;
        if (i >= n8) return;
        const float4 v0 = *reinterpret_cast<const float4*>(src + (size_t)i * 8);
        const float4 v1 = *reinterpret_cast<const float4*>(src + (size_t)i * 8 + 4);
        ushort8v o;
        o[0] = f2bf(v0.x); o[1] = f2bf(v0.y); o[2] = f2bf(v0.z); o[3] = f2bf(v0.w);
        o[4] = f2bf(v1.x); o[5] = f2bf(v1.y); o[6] = f2bf(v1.z); o[7] = f2bf(v1.w);
        *reinterpret_cast<ushort8v*>(dst + (size_t)i * 8) = o;
    } else {
        int idx = (b - 2 * nb1) * 256 + threadIdx.x;
        if (idx >= DIM * KTOT) return;
        int f = idx / KTOT, k = idx % KTOT;
        float v;
        if (k < 1024)       v = relF[(size_t)k * DIM + f];
        else if (k < 1152)  v = rootW[(k - 1024) * DIM + f];
        else                v = skipW[f * DIM + (k - 1152)];
        Bt[(size_t)f * KTOT + k] = f2bf(v);
    }
}

// ---------------------------------------------------------------------------
// CSR build over M = N*8 segments, key = dst*8 + type
// ---------------------------------------------------------------------------
__global__ __launch_bounds__(256) void hist_kernel(
    const int* __restrict__ ei, const int* __restrict__ et,
    int* __restrict__ counts, int E)
{
    int e = blockIdx.x * 256 + threadIdx.x;
    if (e < E) atomicAdd(&counts[ei[(long long)E + e] * 8 + (et[e] & 7)], 1);
}

__global__ __launch_bounds__(256) void scan1_kernel(
    const int* __restrict__ counts, int* __restrict__ local,
    int* __restrict__ blockSums, int M)
{
    __shared__ int sh[256];
    const int b = blockIdx.x, t = threadIdx.x;
    const int base = b * SCAN_CHUNK + t * 8;

    int v[8];
    int s = 0;
    #pragma unroll
    for (int j = 0; j < 8; ++j) {
        int idx = base + j;
        v[j] = (idx < M) ? counts[idx] : 0;
        s += v[j];
    }
    sh[t] = s;
    __syncthreads();
    for (int off = 1; off < 256; off <<= 1) {
        int x = (t >= off) ? sh[t - off] : 0;
        __syncthreads();
        sh[t] += x;
        __syncthreads();
    }
    int ex = sh[t] - s;
    if (t == 255) blockSums[b] = sh[255];
    #pragma unroll
    for (int j = 0; j < 8; ++j) {
        int idx = base + j;
        if (idx < M) { local[idx] = ex; ex += v[j]; }
    }
}

__global__ __launch_bounds__(1024) void scan2_kernel(int* __restrict__ bs, int nb)
{
    __shared__ int sh[1024];
    const int t = threadIdx.x;
    int v = (t < nb) ? bs[t] : 0;
    sh[t] = v;
    __syncthreads();
    for (int off = 1; off < 1024; off <<= 1) {
        int x = (t >= off) ? sh[t - off] : 0;
        __syncthreads();
        sh[t] += x;
        __syncthreads();
    }
    if (t < nb) bs[t] = sh[t] - v;
}

__global__ __launch_bounds__(256) void scan3_kernel(
    int* __restrict__ offsets, const int* __restrict__ blockSums,
    int* __restrict__ cursor, int M, int E)
{
    const int b = blockIdx.x, t = threadIdx.x;
    const int add = blockSums[b];
    #pragma unroll
    for (int j = 0; j < 8; ++j) {
        int idx = b * SCAN_CHUNK + j * 256 + t;
        if (idx < M) {
            int v = offsets[idx] + add;
            offsets[idx] = v;
            cursor[idx]  = v;
        }
    }
    if (b == 0 && t == 0) offsets[M] = E;
}

// sort edge payloads by (dst,type): payload[pos] = (src, bits(weight))
__global__ __launch_bounds__(256) void scatter_kernel(
    const int* __restrict__ ei, const int* __restrict__ et,
    const float* __restrict__ ew, int* __restrict__ cursor,
    int2* __restrict__ payload, int E)
{
    int e = blockIdx.x * 256 + threadIdx.x;
    if (e < E) {
        int key = ei[(long long)E + e] * 8 + (et[e] & 7);
        int pos = atomicAdd(&cursor[key], 1);
        payload[pos] = make_int2(ei[e], __float_as_int(ew[e]));
    }
}

// ---------------------------------------------------------------------------
// accum: one quarter-wave per (node,type) segment. 16 lanes x 16 B = 256 B
// row per gather. bf16 pairs converted via u<<16 / u&0xffff0000 (2 ops/pair).
// S[q*128 + :] = sum_{e in seg} ew[e]*hb[src,:]
// ---------------------------------------------------------------------------
__global__ __launch_bounds__(256) void accum_kernel(
    const int2* __restrict__ payload, const unsigned short* __restrict__ hb,
    const int* __restrict__ offsets, unsigned short* __restrict__ S, int M)
{
    const int tid = threadIdx.x;
    const int q   = blockIdx.x * 16 + (tid >> 4);   // segment id
    const int l16 = tid & 15;
    if (q >= M) return;

    const int s0 = offsets[q];
    const int s1 = offsets[q + 1];

    float acc[8] = {0.f, 0.f, 0.f, 0.f, 0.f, 0.f, 0.f, 0.f};
    int o = s0;
    for (; o + 2 <= s1; o += 2) {
        const int2 p0 = payload[o];
        const int2 p1 = payload[o + 1];
        const uint4v h0 = *reinterpret_cast<const uint4v*>(
            hb + (size_t)p0.x * DIM + l16 * 8);
        const uint4v h1 = *reinterpret_cast<const uint4v*>(
            hb + (size_t)p1.x * DIM + l16 * 8);
        const float w0 = __int_as_float(p0.y);
        const float w1 = __int_as_float(p1.y);
        #pragma unroll
        for (int i = 0; i < 4; ++i) {
            acc[2 * i]     += w0 * bits2f(h0[i] << 16)
                            + w1 * bits2f(h1[i] << 16);
            acc[2 * i + 1] += w0 * bits2f(h0[i] & 0xffff0000u)
                            + w1 * bits2f(h1[i] & 0xffff0000u);
        }
    }
    if (o < s1) {
        const int2 p0 = payload[o];
        const uint4v h0 = *reinterpret_cast<const uint4v*>(
            hb + (size_t)p0.x * DIM + l16 * 8);
        const float w0 = __int_as_float(p0.y);
        #pragma unroll
        for (int i = 0; i < 4; ++i) {
            acc[2 * i]     += w0 * bits2f(h0[i] << 16);
            acc[2 * i + 1] += w0 * bits2f(h0[i] & 0xffff0000u);
        }
    }

    uint4v pk;
    #pragma unroll
    for (int i = 0; i < 4; ++i)
        pk[i] = (unsigned)f2bf(acc[2 * i]) | ((unsigned)f2bf(acc[2 * i + 1]) << 16);
    *reinterpret_cast<uint4v*>(&S[(size_t)q * 128 + l16 * 8]) = pk;
}

// ---------------------------------------------------------------------------
// out[n0+i][j] = sum_k A[i][k]*B[k][j] + bias[j] + skipB[j]
// A = [S | hb | xb] (all bf16), B from Bt.
// BM=32, BN=128, BK=64; 128 threads = 2 waves, wave w -> cols [w*64,w*64+64),
// rows [0,32): acc[2][4]. Grid ceil(N/32)=1563 blocks -> ~6 blocks/CU.
// Single-buffered: gload_lds x16 DMA (linear LDS dest, inverse-XOR source)
// -> barrier -> MFMA (swizzled ds_read) -> barrier. 20 KB LDS.
// ---------------------------------------------------------------------------
__global__ __launch_bounds__(128) void mfma_gemm_kernel(
    const unsigned short* __restrict__ S, const unsigned short* __restrict__ hb,
    const unsigned short* __restrict__ xb, const unsigned short* __restrict__ Bt,
    const float* __restrict__ bias, const float* __restrict__ skipB,
    float* __restrict__ out, int N)
{
    __shared__ unsigned short As[32 * 64];    // [row][k] swizzled, 4 KiB
    __shared__ unsigned short Bs[128 * 64];   // [col][k] swizzled, 16 KiB

    const int tid  = threadIdx.x;
    const int lane = tid & 63;
    const int wid  = tid >> 6;               // 0..1
    const int l15  = lane & 15, l4 = lane >> 4;
    const int n0   = blockIdx.x * 32;

    // per-lane staging geometry
    // A: 256 chunks (32 rows x 8), 2 per thread; chunk c = i*128 + tid
    int aC8[2], aN[2];
    #pragma unroll
    for (int i = 0; i < 2; ++i) {
        int c   = i * 128 + tid;
        int row = c >> 3;
        aC8[i]  = (c & 7) ^ (row & 7);        // inverse swizzle on source
        int n   = n0 + row;
        aN[i]   = (n < N) ? n : (N - 1);      // clamp; OOB outputs not stored
    }
    // B: 1024 chunks (128 cols x 8), 8 per thread; chunk c = i*128 + tid
    int bCol[8], bC8[8];
    #pragma unroll
    for (int i = 0; i < 8; ++i) {
        int c   = i * 128 + tid;
        bCol[i] = c >> 3;
        bC8[i]  = (c & 7) ^ (bCol[i] & 7);
    }

    float4v acc[2][4];
    #pragma unroll
    for (int m = 0; m < 2; ++m)
        #pragma unroll
        for (int nn = 0; nn < 4; ++nn)
            acc[m][nn] = (float4v)0.f;

    for (int t = 0; t < 20; ++t) {
        const int k0 = t * 64;
        const unsigned short* __restrict__ A;
        size_t strideA;
        int kb;
        if (t < 16)      { A = S;  strideA = 1024; kb = k0; }
        else if (t < 18) { A = hb; strideA = DIM;  kb = k0 - 1024; }
        else             { A = xb; strideA = DIM;  kb = k0 - 1152; }

        __syncthreads();   // previous tile fully consumed
        // ---- DMA-stage A tile: 2 x (64 lanes x 16 B) per wave ----
        #pragma unroll
        for (int i = 0; i < 2; ++i) {
            gload_lds16(A + (size_t)aN[i] * strideA + kb + aC8[i] * 8,
                        (char*)As + (size_t)(i * 128 + wid * 64) * 16);
        }
        // ---- DMA-stage B tile: 8 x (64 lanes x 16 B) per wave ----
        #pragma unroll
        for (int i = 0; i < 8; ++i) {
            gload_lds16(Bt + (size_t)bCol[i] * KTOT + k0 + bC8[i] * 8,
                        (char*)Bs + (size_t)(i * 128 + wid * 64) * 16);
        }
        __syncthreads();   // compiler drains vmcnt before barrier

        // ---- MFMA: 2 sub-steps of K=32 ----
        #pragma unroll
        for (int s = 0; s < 2; ++s) {
            const int kk = s * 32 + l4 * 8;       // this lane's k start
            short8v a[2], b[4];
            #pragma unroll
            for (int m = 0; m < 2; ++m) {
                int row = m * 16 + l15;
                int bo = row * 128 + ((kk * 2) ^ ((row & 7) << 4));
                a[m] = *reinterpret_cast<const short8v*>((const char*)As + bo);
            }
            #pragma unroll
            for (int nn = 0; nn < 4; ++nn) {
                int col = wid * 64 + nn * 16 + l15;
                int bo = col * 128 + ((kk * 2) ^ ((col & 7) << 4));
                b[nn] = *reinterpret_cast<const short8v*>((const char*)Bs + bo);
            }
            #pragma unroll
            for (int m = 0; m < 2; ++m)
                #pragma unroll
                for (int nn = 0; nn < 4; ++nn)
                    acc[m][nn] = __builtin_amdgcn_mfma_f32_16x16x32_bf16(
                        a[m], b[nn], acc[m][nn], 0, 0, 0);
        }
    }

    // ---- epilogue: out = acc + bias + skipB ----
    #pragma unroll
    for (int nn = 0; nn < 4; ++nn) {
        const int col = wid * 64 + nn * 16 + l15;
        const float bb = bias[col] + skipB[col];
        #pragma unroll
        for (int m = 0; m < 2; ++m) {
            #pragma unroll
            for (int j = 0; j < 4; ++j) {
                int row = m * 16 + l4 * 4 + j;
                int n = n0 + row;
                if (n < N)
                    out[(size_t)n * DIM + col] = acc[m][nn][j] + bb;
            }
        }
    }
}

// ---------------------------------------------------------------------------
// fallback kernels in case ws is too small or R != 8
// ---------------------------------------------------------------------------
__global__ __launch_bounds__(256) void base_kernel(
    const float* __restrict__ x, const float* __restrict__ h,
    const float* __restrict__ skipW, const float* __restrict__ rootW,
    const float* __restrict__ bias, const float* __restrict__ skipB,
    float* __restrict__ out, int N)
{
    __shared__ float As2[BM][KC];
    __shared__ float Bs2[KC][DIM + BPAD];

    const int tid = threadIdx.x;
    const int n0  = blockIdx.x * BM;
    const int f0  = (tid & 31) * 4;
    const int r0  = (tid >> 5) * 8;

    float acc[8][4] = {};

    for (int phase = 0; phase < 2; ++phase) {
        const float* __restrict__ A = phase ? h : x;
        for (int d0 = 0; d0 < DIM; d0 += KC) {
            __syncthreads();
            for (int idx = tid; idx < BM * KC; idx += 256) {
                int r = idx / KC, dd = idx % KC;
                int n = n0 + r;
                As2[r][dd] = (n < N) ? A[(long long)n * DIM + d0 + dd] : 0.f;
            }
            if (phase == 0) {
                for (int idx = tid; idx < DIM * KC; idx += 256) {
                    int f = idx / KC, dd = idx % KC;
                    Bs2[dd][f] = skipW[f * DIM + d0 + dd];
                }
            } else {
                for (int idx = tid; idx < KC * DIM; idx += 256) {
                    int dd = idx / DIM, f = idx % DIM;
                    Bs2[dd][f] = rootW[(d0 + dd) * DIM + f];
                }
            }
            __syncthreads();
            #pragma unroll
            for (int dd = 0; dd < KC; ++dd) {
                float a[8];
                #pragma unroll
                for (int i = 0; i < 8; ++i) a[i] = As2[r0 + i][dd];
                const float4 b = *reinterpret_cast<const float4*>(&Bs2[dd][f0]);
                #pragma unroll
                for (int i = 0; i < 8; ++i) {
                    acc[i][0] += a[i] * b.x; acc[i][1] += a[i] * b.y;
                    acc[i][2] += a[i] * b.z; acc[i][3] += a[i] * b.w;
                }
            }
        }
    }

    float bb[4];
    #pragma unroll
    for (int j = 0; j < 4; ++j) bb[j] = bias[f0 + j] + skipB[f0 + j];
    #pragma unroll
    for (int i = 0; i < 8; ++i) {
        int n = n0 + r0 + i;
        if (n < N) {
            float4 v = make_float4(acc[i][0] + bb[0], acc[i][1] + bb[1],
                                   acc[i][2] + bb[2], acc[i][3] + bb[3]);
            *reinterpret_cast<float4*>(&out[(long long)n * DIM + f0]) = v;
        }
    }
}

__global__ __launch_bounds__(256) void hrel_kernel(
    const float* __restrict__ h, const float* __restrict__ rel,
    float* __restrict__ hrel, int N, int R)
{
    __shared__ float As2[BM][KC];
    __shared__ float Bs2[KC][DIM + BPAD];

    const int tid = threadIdx.x;
    const int n0  = blockIdx.x * BM;
    const int rr  = blockIdx.y;
    const float* __restrict__ B = rel + (size_t)rr * DIM * DIM;
    const int f0  = (tid & 31) * 4;
    const int r0  = (tid >> 5) * 8;

    float acc[8][4] = {};

    for (int d0 = 0; d0 < DIM; d0 += KC) {
        __syncthreads();
        for (int idx = tid; idx < BM * KC; idx += 256) {
            int r = idx / KC, dd = idx % KC;
            int n = n0 + r;
            As2[r][dd] = (n < N) ? h[(long long)n * DIM + d0 + dd] : 0.f;
        }
        for (int idx = tid; idx < KC * DIM; idx += 256) {
            int dd = idx / DIM, f = idx % DIM;
            Bs2[dd][f] = B[(d0 + dd) * DIM + f];
        }
        __syncthreads();
        #pragma unroll
        for (int dd = 0; dd < KC; ++dd) {
            float a[8];
            #pragma unroll
            for (int i = 0; i < 8; ++i) a[i] = As2[r0 + i][dd];
            const float4 b = *reinterpret_cast<const float4*>(&Bs2[dd][f0]);
            #pragma unroll
            for (int i = 0; i < 8; ++i) {
                acc[i][0] += a[i] * b.x; acc[i][1] += a[i] * b.y;
                acc[i][2] += a[i] * b.z; acc[i][3] += a[i] * b.w;
            }
        }
    }

    #pragma unroll
    for (int i = 0; i < 8; ++i) {
        int n = n0 + r0 + i;
        if (n < N) {
            float4 v = make_float4(acc[i][0], acc[i][1], acc[i][2], acc[i][3]);
            *reinterpret_cast<float4*>(&hrel[((long long)n * R + rr) * DIM + f0]) = v;
        }
    }
}

__global__ __launch_bounds__(256) void edge_kernel(
    const int* __restrict__ ei, const int* __restrict__ et,
    const float* __restrict__ ew, const float* __restrict__ hrel,
    float* __restrict__ out, int E, int R)
{
    const int tid  = threadIdx.x;
    const int lane = tid & 31;
    const long long e = (long long)blockIdx.x * 8 + (tid >> 5);
    if (e >= E) return;

    const int   src = ei[e];
    const int   dst = ei[(long long)E + e];
    const int   r   = et[e];
    const float w   = ew[e];

    const float4 v = reinterpret_cast<const float4*>(
        hrel + ((long long)src * R + r) * DIM)[lane];

    float* o = out + (long long)dst * DIM + lane * 4;
    atomicAdd(o + 0, v.x * w);
    atomicAdd(o + 1, v.y * w);
    atomicAdd(o + 2, v.z * w);
    atomicAdd(o + 3, v.w * w);
}

__global__ __launch_bounds__(256) void edge_direct_kernel(
    const int* __restrict__ ei, const int* __restrict__ et,
    const float* __restrict__ ew, const float* __restrict__ h,
    const float* __restrict__ rel, float* __restrict__ out, int E)
{
    const int wid  = threadIdx.x >> 6;
    const int lane = threadIdx.x & 63;
    const long long e = (long long)blockIdx.x * 4 + wid;
    if (e >= E) return;

    const int   src = ei[e];
    const int   dst = ei[(long long)E + e];
    const int   r   = et[e];
    const float w   = ew[e];

    const float* __restrict__ hrow = h + (long long)src * DIM;
    const float* __restrict__ W    = rel + (size_t)r * DIM * DIM;

    float acc0 = 0.f, acc1 = 0.f;
    #pragma unroll 8
    for (int d = 0; d < DIM; ++d) {
        float hv = hrow[d];
        acc0 += hv * W[d * DIM + lane];
        acc1 += hv * W[d * DIM + lane + 64];
    }
    atomicAdd(&out[(long long)dst * DIM + lane],      acc0 * w);
    atomicAdd(&out[(long long)dst * DIM + lane + 64], acc1 * w);
}

// ---------------------------------------------------------------------------
extern "C" void kernel_launch(void* const* d_in, const int* in_sizes, int n_in,
                              void* d_out, int out_size, void* d_ws, size_t ws_size,
                              hipStream_t stream)
{
    const float* x     = (const float*)d_in[0];
    const float* h     = (const float*)d_in[1];
    const int*   ei    = (const int*)  d_in[2];
    const int*   et    = (const int*)  d_in[3];
    const float* ew    = (const float*)d_in[4];
    const float* rel   = (const float*)d_in[5];
    const float* rootW = (const float*)d_in[6];
    const float* bias  = (const float*)d_in[7];
    const float* skipW = (const float*)d_in[8];
    const float* skipB = (const float*)d_in[9];
    float* out = (float*)d_out;

    const int N = in_sizes[0] / DIM;           // 50000
    const int E = in_sizes[3];                 // 600000
    const int R = in_sizes[5] / (DIM * DIM);   // 8

    const int M = N * 8;                       // CSR segments = (node, type)
    const int nbScan = (M + SCAN_CHUNK - 1) / SCAN_CHUNK;

    // workspace layout: S | hb | xb | Bt | payload | offsets | cursor | blockSums
    const size_t S_elems  = (size_t)N * 1024;          // bf16
    const size_t hb_elems = (size_t)N * DIM;           // bf16
    const size_t Bt_elems = (size_t)DIM * KTOT;        // bf16
    const size_t head_bytes =
        (S_elems + 2 * hb_elems + Bt_elems) * sizeof(unsigned short);
    const size_t need_new = head_bytes
                          + (size_t)E * sizeof(int2)
                          + ((size_t)(M + 1) + M + 1024) * sizeof(int);

    if (R == 8 && nbScan <= 1024 && (head_bytes % 8 == 0) && ws_size >= need_new) {
        unsigned short* S  = (unsigned short*)d_ws;
        unsigned short* hb = S + S_elems;
        unsigned short* xb = hb + hb_elems;
        unsigned short* Bt = xb + hb_elems;
        int2*  payload   = (int2*)((char*)d_ws + head_bytes);  // E (8B-aligned)
        int*   offsets   = (int*)(payload + E);                // M+1
        int*   cursor    = offsets + (M + 1);                  // M
        int*   blockSums = cursor + M;                         // 1024

        const int n8  = N * DIM / 8;
        const int nb1 = (n8 + 255) / 256;
        const int nbB = (DIM * KTOT + 255) / 256;

        hipMemsetAsync(cursor, 0, (size_t)M * sizeof(int), stream);
        hist_kernel<<<dim3((E + 255) / 256), 256, 0, stream>>>(ei, et, cursor, E);
        scan1_kernel<<<dim3(nbScan), 256, 0, stream>>>(cursor, offsets, blockSums, M);
        scan2_kernel<<<dim3(1), 1024, 0, stream>>>(blockSums, nbScan);
        scan3_kernel<<<dim3(nbScan), 256, 0, stream>>>(offsets, blockSums, cursor, M, E);
        scatter_kernel<<<dim3((E + 255) / 256), 256, 0, stream>>>(
            ei, et, ew, cursor, payload, E);
        prep_kernel<<<dim3(2 * nb1 + nbB), 256, 0, stream>>>(
            h, x, rel, rootW, skipW, hb, xb, Bt, n8, nb1);
        accum_kernel<<<dim3((M + 15) / 16), 256, 0, stream>>>(
            payload, hb, offsets, S, M);
        mfma_gemm_kernel<<<dim3((N + 31) / 32), 128, 0, stream>>>(
            S, hb, xb, Bt, bias, skipB, out, N);
    } else {
        base_kernel<<<dim3((N + BM - 1) / BM), 256, 0, stream>>>(
            x, h, skipW, rootW, bias, skipB, out, N);
        if (ws_size >= (size_t)N * R * DIM * sizeof(float)) {
            float* hrel = (float*)d_ws;
            hrel_kernel<<<dim3((N + BM - 1) / BM, R), 256, 0, stream>>>(h, rel, hrel, N, R);
            edge_kernel<<<dim3((E + 7) / 8), 256, 0, stream>>>(ei, et, ew, hrel, out, E, R);
        } else {
            edge_direct_kernel<<<dim3((E + 3) / 4), 256, 0, stream>>>(ei, et, ew, h, rel, out, E);
        }
    }
}

// Round 16
// 162.139 us; speedup vs baseline: 1.0687x; 1.0687x over previous
//
#include <hip/hip_runtime.h>

// RGCN layer with skip on MI355X.
// out[n] = bias + skip_bias + x[n]@skipW^T + h[n]@rootW + sum_{e: dst=n} ew[e]*(h[src]@rel[etype])
//
// Round 16: revert GEMM to round-14 config (BM=64/256thr/24KB LDS; round-15's
// BM=32/128thr regressed: same waves/CU product, halved DMA width, 2x Bt
// traffic). Merge hist+prep into ONE dispatch (block-range split): both are
// dependency-free front kernels with complementary profiles (atomics vs
// streaming) -> they overlap inside one dispatch instead of serializing.

constexpr int DIM  = 128;
constexpr int BM   = 64;
constexpr int KC   = 32;
constexpr int BPAD = 4;
constexpr int KTOT = 1280;        // 8*128 (S) + 128 (h) + 128 (x)
constexpr int SCAN_CHUNK = 2048;  // elements per scan block (256 thr x 8)

typedef __attribute__((ext_vector_type(8))) short     short8v;
typedef __attribute__((ext_vector_type(8))) unsigned short ushort8v;
typedef __attribute__((ext_vector_type(4))) float     float4v;
typedef __attribute__((ext_vector_type(4))) unsigned  uint4v;

__device__ __forceinline__ unsigned short f2bf(float x) {
    union { float f; unsigned u; } c; c.f = x;
    unsigned u = c.u;
    u += 0x7fffu + ((u >> 16) & 1u);   // round-to-nearest-even
    return (unsigned short)(u >> 16);
}
__device__ __forceinline__ float bits2f(unsigned u) {
    union { unsigned u; float f; } c; c.u = u; return c.f;
}

// async global->LDS, 16 B per lane; LDS dest = wave-uniform base + lane*16
__device__ __forceinline__ void gload_lds16(const void* g, void* l) {
    __builtin_amdgcn_global_load_lds(
        (const __attribute__((address_space(1))) unsigned int*)g,
        (__attribute__((address_space(3))) unsigned int*)l,
        16, 0, 0);
}

// ---------------------------------------------------------------------------
// merged front kernel (all dependency-free work in ONE dispatch):
//   blocks [0, nbH)              : histogram counts[dst*8+type]
//   blocks [nbH, nbH+nb1)        : cvt h  -> hb (bf16)
//   blocks [nbH+nb1, nbH+2*nb1)  : cvt x  -> xb (bf16)
//   blocks [nbH+2*nb1, ...+nbB)  : repack Bt
// Bt[f][k]: k<1024 -> relF[k][f]; 1024..1151 -> rootW[k-1024][f];
//           1152..1279 -> skipW[f][k-1152]
// ---------------------------------------------------------------------------
__global__ __launch_bounds__(256) void hist_prep_kernel(
    const int* __restrict__ ei, const int* __restrict__ et,
    int* __restrict__ counts, int E,
    const float* __restrict__ h, const float* __restrict__ x,
    const float* __restrict__ relF, const float* __restrict__ rootW,
    const float* __restrict__ skipW,
    unsigned short* __restrict__ hb, unsigned short* __restrict__ xb,
    unsigned short* __restrict__ Bt, int n8, int nbH, int nb1)
{
    const int b = blockIdx.x;
    if (b < nbH) {
        int e = b * 256 + threadIdx.x;
        if (e < E) atomicAdd(&counts[ei[(long long)E + e] * 8 + (et[e] & 7)], 1);
    } else if (b < nbH + 2 * nb1) {
        const int bb = b - nbH;
        const float* __restrict__ src = (bb < nb1) ? h : x;
        unsigned short* __restrict__ dst = (bb < nb1) ? hb : xb;
        int i = (bb < nb1 ? bb : bb - nb1) * 256 + threadIdx.x;
        if (i >= n8) return;
        const float4 v0 = *reinterpret_cast<const float4*>(src + (size_t)i * 8);
        const float4 v1 = *reinterpret_cast<const float4*>(src + (size_t)i * 8 + 4);
        ushort8v o;
        o[0] = f2bf(v0.x); o[1] = f2bf(v0.y); o[2] = f2bf(v0.z); o[3] = f2bf(v0.w);
        o[4] = f2bf(v1.x); o[5] = f2bf(v1.y); o[6] = f2bf(v1.z); o[7] = f2bf(v1.w);
        *reinterpret_cast<ushort8v*>(dst + (size_t)i * 8) = o;
    } else {
        int idx = (b - nbH - 2 * nb1) * 256 + threadIdx.x;
        if (idx >= DIM * KTOT) return;
        int f = idx / KTOT, k = idx % KTOT;
        float v;
        if (k < 1024)       v = relF[(size_t)k * DIM + f];
        else if (k < 1152)  v = rootW[(k - 1024) * DIM + f];
        else                v = skipW[f * DIM + (k - 1152)];
        Bt[(size_t)f * KTOT + k] = f2bf(v);
    }
}

// ---------------------------------------------------------------------------
// hierarchical scan over M = N*8 segment counts
// ---------------------------------------------------------------------------
__global__ __launch_bounds__(256) void scan1_kernel(
    const int* __restrict__ counts, int* __restrict__ local,
    int* __restrict__ blockSums, int M)
{
    __shared__ int sh[256];
    const int b = blockIdx.x, t = threadIdx.x;
    const int base = b * SCAN_CHUNK + t * 8;

    int v[8];
    int s = 0;
    #pragma unroll
    for (int j = 0; j < 8; ++j) {
        int idx = base + j;
        v[j] = (idx < M) ? counts[idx] : 0;
        s += v[j];
    }
    sh[t] = s;
    __syncthreads();
    for (int off = 1; off < 256; off <<= 1) {
        int x = (t >= off) ? sh[t - off] : 0;
        __syncthreads();
        sh[t] += x;
        __syncthreads();
    }
    int ex = sh[t] - s;
    if (t == 255) blockSums[b] = sh[255];
    #pragma unroll
    for (int j = 0; j < 8; ++j) {
        int idx = base + j;
        if (idx < M) { local[idx] = ex; ex += v[j]; }
    }
}

__global__ __launch_bounds__(1024) void scan2_kernel(int* __restrict__ bs, int nb)
{
    __shared__ int sh[1024];
    const int t = threadIdx.x;
    int v = (t < nb) ? bs[t] : 0;
    sh[t] = v;
    __syncthreads();
    for (int off = 1; off < 1024; off <<= 1) {
        int x = (t >= off) ? sh[t - off] : 0;
        __syncthreads();
        sh[t] += x;
        __syncthreads();
    }
    if (t < nb) bs[t] = sh[t] - v;
}

__global__ __launch_bounds__(256) void scan3_kernel(
    int* __restrict__ offsets, const int* __restrict__ blockSums,
    int* __restrict__ cursor, int M, int E)
{
    const int b = blockIdx.x, t = threadIdx.x;
    const int add = blockSums[b];
    #pragma unroll
    for (int j = 0; j < 8; ++j) {
        int idx = b * SCAN_CHUNK + j * 256 + t;
        if (idx < M) {
            int v = offsets[idx] + add;
            offsets[idx] = v;
            cursor[idx]  = v;
        }
    }
    if (b == 0 && t == 0) offsets[M] = E;
}

// sort edge payloads by (dst,type): payload[pos] = (src, bits(weight))
__global__ __launch_bounds__(256) void scatter_kernel(
    const int* __restrict__ ei, const int* __restrict__ et,
    const float* __restrict__ ew, int* __restrict__ cursor,
    int2* __restrict__ payload, int E)
{
    int e = blockIdx.x * 256 + threadIdx.x;
    if (e < E) {
        int key = ei[(long long)E + e] * 8 + (et[e] & 7);
        int pos = atomicAdd(&cursor[key], 1);
        payload[pos] = make_int2(ei[e], __float_as_int(ew[e]));
    }
}

// ---------------------------------------------------------------------------
// accum: one quarter-wave per (node,type) segment. 16 lanes x 16 B = 256 B
// row per gather. bf16 pairs converted via u<<16 / u&0xffff0000 (2 ops/pair).
// S[q*128 + :] = sum_{e in seg} ew[e]*hb[src,:]
// ---------------------------------------------------------------------------
__global__ __launch_bounds__(256) void accum_kernel(
    const int2* __restrict__ payload, const unsigned short* __restrict__ hb,
    const int* __restrict__ offsets, unsigned short* __restrict__ S, int M)
{
    const int tid = threadIdx.x;
    const int q   = blockIdx.x * 16 + (tid >> 4);   // segment id
    const int l16 = tid & 15;
    if (q >= M) return;

    const int s0 = offsets[q];
    const int s1 = offsets[q + 1];

    float acc[8] = {0.f, 0.f, 0.f, 0.f, 0.f, 0.f, 0.f, 0.f};
    int o = s0;
    for (; o + 2 <= s1; o += 2) {
        const int2 p0 = payload[o];
        const int2 p1 = payload[o + 1];
        const uint4v h0 = *reinterpret_cast<const uint4v*>(
            hb + (size_t)p0.x * DIM + l16 * 8);
        const uint4v h1 = *reinterpret_cast<const uint4v*>(
            hb + (size_t)p1.x * DIM + l16 * 8);
        const float w0 = __int_as_float(p0.y);
        const float w1 = __int_as_float(p1.y);
        #pragma unroll
        for (int i = 0; i < 4; ++i) {
            acc[2 * i]     += w0 * bits2f(h0[i] << 16)
                            + w1 * bits2f(h1[i] << 16);
            acc[2 * i + 1] += w0 * bits2f(h0[i] & 0xffff0000u)
                            + w1 * bits2f(h1[i] & 0xffff0000u);
        }
    }
    if (o < s1) {
        const int2 p0 = payload[o];
        const uint4v h0 = *reinterpret_cast<const uint4v*>(
            hb + (size_t)p0.x * DIM + l16 * 8);
        const float w0 = __int_as_float(p0.y);
        #pragma unroll
        for (int i = 0; i < 4; ++i) {
            acc[2 * i]     += w0 * bits2f(h0[i] << 16);
            acc[2 * i + 1] += w0 * bits2f(h0[i] & 0xffff0000u);
        }
    }

    uint4v pk;
    #pragma unroll
    for (int i = 0; i < 4; ++i)
        pk[i] = (unsigned)f2bf(acc[2 * i]) | ((unsigned)f2bf(acc[2 * i + 1]) << 16);
    *reinterpret_cast<uint4v*>(&S[(size_t)q * 128 + l16 * 8]) = pk;
}

// ---------------------------------------------------------------------------
// out[n0+i][j] = sum_k A[i][k]*B[k][j] + bias[j] + skipB[j]
// A = [S | hb | xb] (all bf16), B from Bt.
// BM=64, BN=128, BK=64; 4 waves 2x2 (wave tile 32x64, acc[2][4]).
// Single-buffered: stage (gload_lds x16 DMA, linear LDS dest, inverse-XOR
// source) -> barrier -> MFMA (swizzled ds_read) -> barrier. 24 KB LDS.
// ---------------------------------------------------------------------------
__global__ __launch_bounds__(256) void mfma_gemm_kernel(
    const unsigned short* __restrict__ S, const unsigned short* __restrict__ hb,
    const unsigned short* __restrict__ xb, const unsigned short* __restrict__ Bt,
    const float* __restrict__ bias, const float* __restrict__ skipB,
    float* __restrict__ out, int N)
{
    __shared__ unsigned short As[64 * 64];    // [row][k] swizzled, 8 KiB
    __shared__ unsigned short Bs[128 * 64];   // [col][k] swizzled, 16 KiB

    const int tid  = threadIdx.x;
    const int lane = tid & 63;
    const int wid  = tid >> 6;
    const int wr   = wid >> 1, wc = wid & 1;
    const int l15  = lane & 15, l4 = lane >> 4;
    const int n0   = blockIdx.x * 64;

    // precomputed per-lane staging geometry
    // A: chunks cA = wid*128 + i*64 + lane (i=0,1); 16 B each; row = c>>3
    int aRow[2], aC8[2];
    #pragma unroll
    for (int i = 0; i < 2; ++i) {
        int c = wid * 128 + i * 64 + lane;
        aRow[i] = c >> 3;
        aC8[i]  = (c & 7) ^ (aRow[i] & 7);      // inverse swizzle on source
    }
    int aN[2];
    #pragma unroll
    for (int i = 0; i < 2; ++i) {
        int n = n0 + aRow[i];
        aN[i] = (n < N) ? n : (N - 1);          // clamp; OOB outputs not stored
    }
    // B: chunks cB = wid*256 + i*64 + lane (i=0..3); col = c>>3
    int bCol[4], bC8[4];
    #pragma unroll
    for (int i = 0; i < 4; ++i) {
        int c = wid * 256 + i * 64 + lane;
        bCol[i] = c >> 3;
        bC8[i]  = (c & 7) ^ (bCol[i] & 7);
    }

    float4v acc[2][4];
    #pragma unroll
    for (int m = 0; m < 2; ++m)
        #pragma unroll
        for (int nn = 0; nn < 4; ++nn)
            acc[m][nn] = (float4v)0.f;

    for (int t = 0; t < 20; ++t) {
        const int k0 = t * 64;
        const unsigned short* __restrict__ A;
        size_t strideA;
        int kb;
        if (t < 16)      { A = S;  strideA = 1024; kb = k0; }
        else if (t < 18) { A = hb; strideA = DIM;  kb = k0 - 1024; }
        else             { A = xb; strideA = DIM;  kb = k0 - 1152; }

        __syncthreads();   // previous tile fully consumed
        // ---- DMA-stage A tile: 2 x (64 lanes x 16 B) per wave ----
        #pragma unroll
        for (int i = 0; i < 2; ++i) {
            gload_lds16(A + (size_t)aN[i] * strideA + kb + aC8[i] * 8,
                        (char*)As + (size_t)(wid * 128 + i * 64) * 16);
        }
        // ---- DMA-stage B tile: 4 x (64 lanes x 16 B) per wave ----
        #pragma unroll
        for (int i = 0; i < 4; ++i) {
            gload_lds16(Bt + (size_t)bCol[i] * KTOT + k0 + bC8[i] * 8,
                        (char*)Bs + (size_t)(wid * 256 + i * 64) * 16);
        }
        __syncthreads();   // compiler drains vmcnt before barrier

        // ---- MFMA: 2 sub-steps of K=32 ----
        #pragma unroll
        for (int s = 0; s < 2; ++s) {
            const int kk = s * 32 + l4 * 8;       // this lane's k start
            short8v a[2], b[4];
            #pragma unroll
            for (int m = 0; m < 2; ++m) {
                int row = wr * 32 + m * 16 + l15;
                int bo = row * 128 + ((kk * 2) ^ ((row & 7) << 4));
                a[m] = *reinterpret_cast<const short8v*>((const char*)As + bo);
            }
            #pragma unroll
            for (int nn = 0; nn < 4; ++nn) {
                int col = wc * 64 + nn * 16 + l15;
                int bo = col * 128 + ((kk * 2) ^ ((col & 7) << 4));
                b[nn] = *reinterpret_cast<const short8v*>((const char*)Bs + bo);
            }
            #pragma unroll
            for (int m = 0; m < 2; ++m)
                #pragma unroll
                for (int nn = 0; nn < 4; ++nn)
                    acc[m][nn] = __builtin_amdgcn_mfma_f32_16x16x32_bf16(
                        a[m], b[nn], acc[m][nn], 0, 0, 0);
        }
    }

    // ---- epilogue: out = acc + bias + skipB ----
    #pragma unroll
    for (int nn = 0; nn < 4; ++nn) {
        const int col = wc * 64 + nn * 16 + l15;
        const float bb = bias[col] + skipB[col];
        #pragma unroll
        for (int m = 0; m < 2; ++m) {
            #pragma unroll
            for (int j = 0; j < 4; ++j) {
                int row = wr * 32 + m * 16 + l4 * 4 + j;
                int n = n0 + row;
                if (n < N)
                    out[(size_t)n * DIM + col] = acc[m][nn][j] + bb;
            }
        }
    }
}

// ---------------------------------------------------------------------------
// fallback kernels in case ws is too small or R != 8
// ---------------------------------------------------------------------------
__global__ __launch_bounds__(256) void base_kernel(
    const float* __restrict__ x, const float* __restrict__ h,
    const float* __restrict__ skipW, const float* __restrict__ rootW,
    const float* __restrict__ bias, const float* __restrict__ skipB,
    float* __restrict__ out, int N)
{
    __shared__ float As2[BM][KC];
    __shared__ float Bs2[KC][DIM + BPAD];

    const int tid = threadIdx.x;
    const int n0  = blockIdx.x * BM;
    const int f0  = (tid & 31) * 4;
    const int r0  = (tid >> 5) * 8;

    float acc[8][4] = {};

    for (int phase = 0; phase < 2; ++phase) {
        const float* __restrict__ A = phase ? h : x;
        for (int d0 = 0; d0 < DIM; d0 += KC) {
            __syncthreads();
            for (int idx = tid; idx < BM * KC; idx += 256) {
                int r = idx / KC, dd = idx % KC;
                int n = n0 + r;
                As2[r][dd] = (n < N) ? A[(long long)n * DIM + d0 + dd] : 0.f;
            }
            if (phase == 0) {
                for (int idx = tid; idx < DIM * KC; idx += 256) {
                    int f = idx / KC, dd = idx % KC;
                    Bs2[dd][f] = skipW[f * DIM + d0 + dd];
                }
            } else {
                for (int idx = tid; idx < KC * DIM; idx += 256) {
                    int dd = idx / DIM, f = idx % DIM;
                    Bs2[dd][f] = rootW[(d0 + dd) * DIM + f];
                }
            }
            __syncthreads();
            #pragma unroll
            for (int dd = 0; dd < KC; ++dd) {
                float a[8];
                #pragma unroll
                for (int i = 0; i < 8; ++i) a[i] = As2[r0 + i][dd];
                const float4 b = *reinterpret_cast<const float4*>(&Bs2[dd][f0]);
                #pragma unroll
                for (int i = 0; i < 8; ++i) {
                    acc[i][0] += a[i] * b.x; acc[i][1] += a[i] * b.y;
                    acc[i][2] += a[i] * b.z; acc[i][3] += a[i] * b.w;
                }
            }
        }
    }

    float bb[4];
    #pragma unroll
    for (int j = 0; j < 4; ++j) bb[j] = bias[f0 + j] + skipB[f0 + j];
    #pragma unroll
    for (int i = 0; i < 8; ++i) {
        int n = n0 + r0 + i;
        if (n < N) {
            float4 v = make_float4(acc[i][0] + bb[0], acc[i][1] + bb[1],
                                   acc[i][2] + bb[2], acc[i][3] + bb[3]);
            *reinterpret_cast<float4*>(&out[(long long)n * DIM + f0]) = v;
        }
    }
}

__global__ __launch_bounds__(256) void hrel_kernel(
    const float* __restrict__ h, const float* __restrict__ rel,
    float* __restrict__ hrel, int N, int R)
{
    __shared__ float As2[BM][KC];
    __shared__ float Bs2[KC][DIM + BPAD];

    const int tid = threadIdx.x;
    const int n0  = blockIdx.x * BM;
    const int rr  = blockIdx.y;
    const float* __restrict__ B = rel + (size_t)rr * DIM * DIM;
    const int f0  = (tid & 31) * 4;
    const int r0  = (tid >> 5) * 8;

    float acc[8][4] = {};

    for (int d0 = 0; d0 < DIM; d0 += KC) {
        __syncthreads();
        for (int idx = tid; idx < BM * KC; idx += 256) {
            int r = idx / KC, dd = idx % KC;
            int n = n0 + r;
            As2[r][dd] = (n < N) ? h[(long long)n * DIM + d0 + dd] : 0.f;
        }
        for (int idx = tid; idx < KC * DIM; idx += 256) {
            int dd = idx / DIM, f = idx % DIM;
            Bs2[dd][f] = B[(d0 + dd) * DIM + f];
        }
        __syncthreads();
        #pragma unroll
        for (int dd = 0; dd < KC; ++dd) {
            float a[8];
            #pragma unroll
            for (int i = 0; i < 8; ++i) a[i] = As2[r0 + i][dd];
            const float4 b = *reinterpret_cast<const float4*>(&Bs2[dd][f0]);
            #pragma unroll
            for (int i = 0; i < 8; ++i) {
                acc[i][0] += a[i] * b.x; acc[i][1] += a[i] * b.y;
                acc[i][2] += a[i] * b.z; acc[i][3] += a[i] * b.w;
            }
        }
    }

    #pragma unroll
    for (int i = 0; i < 8; ++i) {
        int n = n0 + r0 + i;
        if (n < N) {
            float4 v = make_float4(acc[i][0], acc[i][1], acc[i][2], acc[i][3]);
            *reinterpret_cast<float4*>(&hrel[((long long)n * R + rr) * DIM + f0]) = v;
        }
    }
}

__global__ __launch_bounds__(256) void edge_kernel(
    const int* __restrict__ ei, const int* __restrict__ et,
    const float* __restrict__ ew, const float* __restrict__ hrel,
    float* __restrict__ out, int E, int R)
{
    const int tid  = threadIdx.x;
    const int lane = tid & 31;
    const long long e = (long long)blockIdx.x * 8 + (tid >> 5);
    if (e >= E) return;

    const int   src = ei[e];
    const int   dst = ei[(long long)E + e];
    const int   r   = et[e];
    const float w   = ew[e];

    const float4 v = reinterpret_cast<const float4*>(
        hrel + ((long long)src * R + r) * DIM)[lane];

    float* o = out + (long long)dst * DIM + lane * 4;
    atomicAdd(o + 0, v.x * w);
    atomicAdd(o + 1, v.y * w);
    atomicAdd(o + 2, v.z * w);
    atomicAdd(o + 3, v.w * w);
}

__global__ __launch_bounds__(256) void edge_direct_kernel(
    const int* __restrict__ ei, const int* __restrict__ et,
    const float* __restrict__ ew, const float* __restrict__ h,
    const float* __restrict__ rel, float* __restrict__ out, int E)
{
    const int wid  = threadIdx.x >> 6;
    const int lane = threadIdx.x & 63;
    const long long e = (long long)blockIdx.x * 4 + wid;
    if (e >= E) return;

    const int   src = ei[e];
    const int   dst = ei[(long long)E + e];
    const int   r   = et[e];
    const float w   = ew[e];

    const float* __restrict__ hrow = h + (long long)src * DIM;
    const float* __restrict__ W    = rel + (size_t)r * DIM * DIM;

    float acc0 = 0.f, acc1 = 0.f;
    #pragma unroll 8
    for (int d = 0; d < DIM; ++d) {
        float hv = hrow[d];
        acc0 += hv * W[d * DIM + lane];
        acc1 += hv * W[d * DIM + lane + 64];
    }
    atomicAdd(&out[(long long)dst * DIM + lane],      acc0 * w);
    atomicAdd(&out[(long long)dst * DIM + lane + 64], acc1 * w);
}

// ---------------------------------------------------------------------------
extern "C" void kernel_launch(void* const* d_in, const int* in_sizes, int n_in,
                              void* d_out, int out_size, void* d_ws, size_t ws_size,
                              hipStream_t stream)
{
    const float* x     = (const float*)d_in[0];
    const float* h     = (const float*)d_in[1];
    const int*   ei    = (const int*)  d_in[2];
    const int*   et    = (const int*)  d_in[3];
    const float* ew    = (const float*)d_in[4];
    const float* rel   = (const float*)d_in[5];
    const float* rootW = (const float*)d_in[6];
    const float* bias  = (const float*)d_in[7];
    const float* skipW = (const float*)d_in[8];
    const float* skipB = (const float*)d_in[9];
    float* out = (float*)d_out;

    const int N = in_sizes[0] / DIM;           // 50000
    const int E = in_sizes[3];                 // 600000
    const int R = in_sizes[5] / (DIM * DIM);   // 8

    const int M = N * 8;                       // CSR segments = (node, type)
    const int nbScan = (M + SCAN_CHUNK - 1) / SCAN_CHUNK;

    // workspace layout: S | hb | xb | Bt | payload | offsets | cursor | blockSums
    const size_t S_elems  = (size_t)N * 1024;          // bf16
    const size_t hb_elems = (size_t)N * DIM;           // bf16
    const size_t Bt_elems = (size_t)DIM * KTOT;        // bf16
    const size_t head_bytes =
        (S_elems + 2 * hb_elems + Bt_elems) * sizeof(unsigned short);
    const size_t need_new = head_bytes
                          + (size_t)E * sizeof(int2)
                          + ((size_t)(M + 1) + M + 1024) * sizeof(int);

    if (R == 8 && nbScan <= 1024 && (head_bytes % 8 == 0) && ws_size >= need_new) {
        unsigned short* S  = (unsigned short*)d_ws;
        unsigned short* hb = S + S_elems;
        unsigned short* xb = hb + hb_elems;
        unsigned short* Bt = xb + hb_elems;
        int2*  payload   = (int2*)((char*)d_ws + head_bytes);  // E (8B-aligned)
        int*   offsets   = (int*)(payload + E);                // M+1
        int*   cursor    = offsets + (M + 1);                  // M
        int*   blockSums = cursor + M;                         // 1024

        const int n8  = N * DIM / 8;
        const int nbH = (E + 255) / 256;
        const int nb1 = (n8 + 255) / 256;
        const int nbB = (DIM * KTOT + 255) / 256;

        hipMemsetAsync(cursor, 0, (size_t)M * sizeof(int), stream);
        hist_prep_kernel<<<dim3(nbH + 2 * nb1 + nbB), 256, 0, stream>>>(
            ei, et, cursor, E, h, x, rel, rootW, skipW, hb, xb, Bt, n8, nbH, nb1);
        scan1_kernel<<<dim3(nbScan), 256, 0, stream>>>(cursor, offsets, blockSums, M);
        scan2_kernel<<<dim3(1), 1024, 0, stream>>>(blockSums, nbScan);
        scan3_kernel<<<dim3(nbScan), 256, 0, stream>>>(offsets, blockSums, cursor, M, E);
        scatter_kernel<<<dim3((E + 255) / 256), 256, 0, stream>>>(
            ei, et, ew, cursor, payload, E);
        accum_kernel<<<dim3((M + 15) / 16), 256, 0, stream>>>(
            payload, hb, offsets, S, M);
        mfma_gemm_kernel<<<dim3((N + 63) / 64), 256, 0, stream>>>(
            S, hb, xb, Bt, bias, skipB, out, N);
    } else {
        base_kernel<<<dim3((N + BM - 1) / BM), 256, 0, stream>>>(
            x, h, skipW, rootW, bias, skipB, out, N);
        if (ws_size >= (size_t)N * R * DIM * sizeof(float)) {
            float* hrel = (float*)d_ws;
            hrel_kernel<<<dim3((N + BM - 1) / BM, R), 256, 0, stream>>>(h, rel, hrel, N, R);
            edge_kernel<<<dim3((E + 7) / 8), 256, 0, stream>>>(ei, et, ew, hrel, out, E, R);
        } else {
            edge_direct_kernel<<<dim3((E + 3) / 4), 256, 0, stream>>>(ei, et, ew, h, rel, out, E);
        }
    }
}